// Round 1
// baseline (302.916 us; speedup 1.0000x reference)
//
#include <hip/hip_runtime.h>

#define N_    2
#define C_    128
#define H_    128
#define W_    128
#define COUT_ 128
#define K_    9
#define HO_   128
#define WO_   128
#define HW_   (H_*W_)
#define CKCHUNK 8                 // channels per chunk
#define CKLEN  (CKCHUNK*K_)       // 72
#define NCHUNK (C_/CKCHUNK)       // 16

__global__ __launch_bounds__(256)
void dcn_fused(const float* __restrict__ x,
               const float* __restrict__ offset,
               const float* __restrict__ mask,
               const float* __restrict__ weight,
               const float* __restrict__ bias,
               float* __restrict__ out)
{
    // 110,592 B LDS total (gfx950 has 160 KiB/CU)
    __shared__ float samp_w[K_*WO_*4];   // 18,432 B  premultiplied bilinear weights
    __shared__ int   samp_a[K_*WO_*4];   // 18,432 B  clamped corner addresses (in-plane)
    __shared__ float w_lds[CKLEN*COUT_]; // 36,864 B  [ck][co]
    __shared__ float cols [CKLEN*WO_];   // 36,864 B  [ck][wo]

    const int tid = threadIdx.x;
    const int n   = blockIdx.x / HO_;
    const int ho  = blockIdx.x % HO_;

    // ---- Phase 0: sampling metadata for this output row -------------------
    for (int e = tid; e < K_*WO_; e += 256) {
        const int k  = e >> 7;          // e / 128
        const int wo = e & (WO_-1);
        const int iy = k / 3, ix = k % 3;
        const int obase = ((n*2*K_ + 2*k)*HO_ + ho)*WO_ + wo;
        const float offy = offset[obase];
        const float offx = offset[obase + HO_*WO_];
        const float m    = mask[((n*K_ + k)*HO_ + ho)*WO_ + wo];
        const float ys = (float)(ho - 1 + iy) + offy;
        const float xs = (float)(wo - 1 + ix) + offx;
        const float y0f = floorf(ys), x0f = floorf(xs);
        const float ly = ys - y0f, lx = xs - x0f;
        const int y0 = (int)y0f, x0i = (int)x0f;
        const int y1 = y0 + 1,  x1  = x0i + 1;
        const float vy0 = (y0  >= 0 && y0  < H_) ? 1.f : 0.f;
        const float vy1 = (y1  >= 0 && y1  < H_) ? 1.f : 0.f;
        const float vx0 = (x0i >= 0 && x0i < W_) ? 1.f : 0.f;
        const float vx1 = (x1  >= 0 && x1  < W_) ? 1.f : 0.f;
        const int y0c = min(max(y0 , 0), H_-1), y1c = min(max(y1, 0), H_-1);
        const int x0c = min(max(x0i, 0), W_-1), x1c = min(max(x1, 0), W_-1);
        samp_a[e*4+0] = y0c*W_ + x0c;
        samp_a[e*4+1] = y0c*W_ + x1c;
        samp_a[e*4+2] = y1c*W_ + x0c;
        samp_a[e*4+3] = y1c*W_ + x1c;
        samp_w[e*4+0] = (1.f-ly)*(1.f-lx)*m*vy0*vx0;
        samp_w[e*4+1] = (1.f-ly)*lx      *m*vy0*vx1;
        samp_w[e*4+2] = ly      *(1.f-lx)*m*vy1*vx0;
        samp_w[e*4+3] = ly      *lx      *m*vy1*vx1;
    }
    __syncthreads();

    float acc[8][8];
    #pragma unroll
    for (int i = 0; i < 8; ++i)
        #pragma unroll
        for (int j = 0; j < 8; ++j) acc[i][j] = 0.f;

    const int co0  = (tid >> 4) * 8;   // 8 couts per thread
    const int pix0 = (tid & 15) * 8;   // 8 pixels per thread

    for (int cc = 0; cc < NCHUNK; ++cc) {
        // stage weight chunk: w_lds[ck][co] (global reads are L2-hot, 590 KB total)
        for (int idx = tid; idx < CKLEN*COUT_; idx += 256) {
            const int co = idx & 127;
            const int ck = idx >> 7;
            w_lds[idx] = weight[co*(C_*K_) + cc*CKLEN + ck];
        }
        // stage deformable columns: cols[ck][wo]
        for (int idx = tid; idx < CKLEN*WO_; idx += 256) {
            const int wo    = idx & 127;
            const int ck    = idx >> 7;
            const int c_sub = ck / K_;
            const int kk    = ck - c_sub*K_;
            const float* plane = x + (size_t)(n*C_ + cc*CKCHUNK + c_sub) * HW_;
            const int e = kk*WO_ + wo;
            const float4 wv = *(const float4*)&samp_w[e*4];
            const int4   av = *(const int4*)  &samp_a[e*4];
            cols[idx] = wv.x*plane[av.x] + wv.y*plane[av.y]
                      + wv.z*plane[av.z] + wv.w*plane[av.w];
        }
        __syncthreads();

        // register-tile GEMM: 8 co x 8 pix per thread
        #pragma unroll 4
        for (int ck = 0; ck < CKLEN; ++ck) {
            const float4 a0 = *(const float4*)&w_lds[ck*COUT_ + co0];
            const float4 a1 = *(const float4*)&w_lds[ck*COUT_ + co0 + 4];
            const float4 b0 = *(const float4*)&cols [ck*WO_   + pix0];
            const float4 b1 = *(const float4*)&cols [ck*WO_   + pix0 + 4];
            const float av[8] = {a0.x,a0.y,a0.z,a0.w,a1.x,a1.y,a1.z,a1.w};
            const float bv[8] = {b0.x,b0.y,b0.z,b0.w,b1.x,b1.y,b1.z,b1.w};
            #pragma unroll
            for (int i = 0; i < 8; ++i)
                #pragma unroll
                for (int j = 0; j < 8; ++j)
                    acc[i][j] = fmaf(av[i], bv[j], acc[i][j]);
        }
        __syncthreads();
    }

    // ---- epilogue: +bias, coalesced float4 stores -------------------------
    #pragma unroll
    for (int i = 0; i < 8; ++i) {
        const int co = co0 + i;
        const float b = bias[co];
        float4 o0 = {acc[i][0]+b, acc[i][1]+b, acc[i][2]+b, acc[i][3]+b};
        float4 o1 = {acc[i][4]+b, acc[i][5]+b, acc[i][6]+b, acc[i][7]+b};
        float* op = out + ((size_t)(n*COUT_ + co)*HO_ + ho)*WO_ + pix0;
        *(float4*)op     = o0;
        *(float4*)(op+4) = o1;
    }
}

extern "C" void kernel_launch(void* const* d_in, const int* in_sizes, int n_in,
                              void* d_out, int out_size, void* d_ws, size_t ws_size,
                              hipStream_t stream) {
    const float* x      = (const float*)d_in[0];
    const float* offset = (const float*)d_in[1];
    const float* mask   = (const float*)d_in[2];
    const float* weight = (const float*)d_in[3];
    const float* bias   = (const float*)d_in[4];
    float* out = (float*)d_out;
    dcn_fused<<<N_*HO_, 256, 0, stream>>>(x, offset, mask, weight, bias, out);
}

// Round 2
// 136.619 us; speedup vs baseline: 2.2172x; 2.2172x over previous
//
#include <hip/hip_runtime.h>

#define N_    2
#define C_    128
#define H_    128
#define W_    128
#define COUT_ 128
#define K_    9
#define HO_   128
#define WO_   128
#define HW_   (H_*W_)

typedef __attribute__((ext_vector_type(8))) short short8v;   // 8 bf16 = 4 VGPR
typedef __attribute__((ext_vector_type(4))) float float4v;

__device__ __forceinline__ unsigned short f2bf(float f) {
    union { float f; unsigned int u; } v; v.f = f;
    return (unsigned short)((v.u + 0x7FFFu + ((v.u >> 16) & 1u)) >> 16);  // RNE
}

// ---- one-time weight pre-pack into MFMA A-fragment order -------------------
// wbuf[((kk*8 + mt)*4 + ks)*64 + lane] = 8 bf16: w[mt*16+(l&15)][ks*32+(l>>4)*8+j][kk]
__global__ __launch_bounds__(256)
void pack_w(const float* __restrict__ w, unsigned short* __restrict__ wb) {
    const int t = blockIdx.x * 256 + threadIdx.x;   // 0 .. 9*8*4*64-1
    if (t >= 9 * 8 * 4 * 64) return;
    const int l  = t & 63;
    const int ks = (t >> 6) & 3;
    const int mt = (t >> 8) & 7;
    const int kk = t >> 11;                          // 0..8
    const int row = mt * 16 + (l & 15);
    const int c0  = ks * 32 + (l >> 4) * 8;
    unsigned short pk[8];
    #pragma unroll
    for (int j = 0; j < 8; ++j)
        pk[j] = f2bf(w[row * (C_ * K_) + (c0 + j) * K_ + kk]);
    *((short8v*)wb + t) = *(short8v*)pk;
}

// ---- fused deformable-im2col + MFMA GEMM -----------------------------------
__global__ __launch_bounds__(256, 2)
void dcn_mfma(const float* __restrict__ x,
              const float* __restrict__ offset,
              const float* __restrict__ mask,
              const unsigned short* __restrict__ wbuf,
              const float* __restrict__ bias,
              float* __restrict__ out)
{
    __shared__ float4 samp_w4[K_ * 64];              //  9.2 KB
    __shared__ int4   samp_a4[K_ * 64];              //  9.2 KB
    __shared__ unsigned short colsT[64 * 128];       // 16.0 KB, XOR-swizzled [wo][c]

    const int tid = threadIdx.x;
    const int bid = blockIdx.x;                      // 512 blocks
    const int n   = bid >> 8;
    const int ho  = (bid >> 1) & 127;
    const int wo0 = (bid & 1) * 64;

    // Phase 0: sampling metadata (premultiplied bilinear*mask*valid + corner addrs)
    for (int e = tid; e < K_ * 64; e += 256) {
        const int k   = e >> 6;
        const int wol = e & 63;
        const int wo  = wo0 + wol;
        const int iy = k / 3, ix = k % 3;
        const int ob = ((n * 2 * K_ + 2 * k) * HO_ + ho) * WO_ + wo;
        const float offy = offset[ob];
        const float offx = offset[ob + HO_ * WO_];
        const float m    = mask[((n * K_ + k) * HO_ + ho) * WO_ + wo];
        const float ys = (float)(ho - 1 + iy) + offy;
        const float xs = (float)(wo - 1 + ix) + offx;
        const float y0f = floorf(ys), x0f = floorf(xs);
        const float ly = ys - y0f, lx = xs - x0f;
        const int y0 = (int)y0f, x0 = (int)x0f;
        const int y1 = y0 + 1,  x1 = x0 + 1;
        const float vy0 = (y0 >= 0 && y0 < H_) ? 1.f : 0.f;
        const float vy1 = (y1 >= 0 && y1 < H_) ? 1.f : 0.f;
        const float vx0 = (x0 >= 0 && x0 < W_) ? 1.f : 0.f;
        const float vx1 = (x1 >= 0 && x1 < W_) ? 1.f : 0.f;
        const int y0c = min(max(y0, 0), H_-1), y1c = min(max(y1, 0), H_-1);
        const int x0c = min(max(x0, 0), W_-1), x1c = min(max(x1, 0), W_-1);
        samp_a4[e] = make_int4(y0c*W_+x0c, y0c*W_+x1c, y1c*W_+x0c, y1c*W_+x1c);
        samp_w4[e] = make_float4((1.f-ly)*(1.f-lx)*m*vy0*vx0,
                                 (1.f-ly)*lx      *m*vy0*vx1,
                                 ly      *(1.f-lx)*m*vy1*vx0,
                                 ly      *lx      *m*vy1*vx1);
    }
    __syncthreads();

    const int lane = tid & 63;
    const int wv   = tid >> 6;          // wave 0..3
    const int mt0  = wv * 2;            // this wave's 2 cout-tiles

    float4v acc[2][4] = {};             // 32 cout x 64 wo per wave

    const float* xn = x + (size_t)n * C_ * HW_;
    const short8v* wb = (const short8v*)wbuf;

    for (int kk = 0; kk < K_; ++kk) {
        // ---- stage colsT[wo][c] (bf16, swizzled) for this kernel tap ------
        {
            const float4 w4 = samp_w4[kk * 64 + lane];
            const int4   av = samp_a4[kk * 64 + lane];
            #pragma unroll
            for (int pass = 0; pass < 4; ++pass) {
                const int c0 = pass * 32 + wv * 8;
                unsigned short pk[8];
                #pragma unroll
                for (int cs = 0; cs < 8; ++cs) {
                    const float* plane = xn + (size_t)(c0 + cs) * HW_;
                    const float v = w4.x * plane[av.x] + w4.y * plane[av.y]
                                  + w4.z * plane[av.z] + w4.w * plane[av.w];
                    pk[cs] = f2bf(v);
                }
                int byte = lane * 256 + c0 * 2;
                byte ^= (lane & 7) << 4;
                *(short8v*)((char*)colsT + byte) = *(short8v*)pk;
            }
        }
        __syncthreads();

        // ---- MFMA: 4 k-steps of 32 over the 128 channels ------------------
        #pragma unroll
        for (int ks = 0; ks < 4; ++ks) {
            const short8v a0 = wb[((kk * 8 + mt0    ) * 4 + ks) * 64 + lane];
            const short8v a1 = wb[((kk * 8 + mt0 + 1) * 4 + ks) * 64 + lane];
            short8v b[4];
            #pragma unroll
            for (int nt = 0; nt < 4; ++nt) {
                const int row  = nt * 16 + (lane & 15);
                int byte = row * 256 + ks * 64 + (lane >> 4) * 16;
                byte ^= (row & 7) << 4;
                b[nt] = *(const short8v*)((const char*)colsT + byte);
            }
            #pragma unroll
            for (int nt = 0; nt < 4; ++nt) {
                acc[0][nt] = __builtin_amdgcn_mfma_f32_16x16x32_bf16(a0, b[nt], acc[0][nt], 0, 0, 0);
                acc[1][nt] = __builtin_amdgcn_mfma_f32_16x16x32_bf16(a1, b[nt], acc[1][nt], 0, 0, 0);
            }
        }
        __syncthreads();
    }

    // ---- epilogue: D layout col=lane&15, row=(lane>>4)*4+reg --------------
    const int colw  = lane & 15;
    const int rquad = (lane >> 4) * 4;
    #pragma unroll
    for (int mi = 0; mi < 2; ++mi) {
        #pragma unroll
        for (int nt = 0; nt < 4; ++nt) {
            const int wo = wo0 + nt * 16 + colw;
            #pragma unroll
            for (int r = 0; r < 4; ++r) {
                const int co = (mt0 + mi) * 16 + rquad + r;
                out[((size_t)(n * COUT_ + co) * HO_ + ho) * WO_ + wo] = acc[mi][nt][r] + bias[co];
            }
        }
    }
}

extern "C" void kernel_launch(void* const* d_in, const int* in_sizes, int n_in,
                              void* d_out, int out_size, void* d_ws, size_t ws_size,
                              hipStream_t stream) {
    const float* x      = (const float*)d_in[0];
    const float* offset = (const float*)d_in[1];
    const float* mask   = (const float*)d_in[2];
    const float* weight = (const float*)d_in[3];
    const float* bias   = (const float*)d_in[4];
    float* out = (float*)d_out;
    unsigned short* wbuf = (unsigned short*)d_ws;    // 294,912 B needed

    pack_w<<<72, 256, 0, stream>>>(weight, wbuf);
    dcn_mfma<<<N_ * HO_ * 2, 256, 0, stream>>>(x, offset, mask, wbuf, bias, out);
}